// Round 6
// baseline (1550.017 us; speedup 1.0000x reference)
//
#include <hip/hip_runtime.h>
#include <hip/hip_fp16.h>
#include <stdint.h>

#define BATCH 4096
#define N_IN  512
#define H1    1536
#define H2    1536
#define N_OUT 512
#define E0 (H1 * 32)
#define E1 (H2 * 32)
#define E2 (N_OUT * 32)
#define ETOT (E0 + E1 + E2)
#define NNODES (H1 + H2 + N_OUT)   // 3584
#define MAXDEG 128

// ---- workspace layout (bytes), total ~37.24 MB (< 38.7 MB proven safe in R1) ----
// nv    : 4096 rows x 4096 cols x 2B fp16 = 33,554,432
//         rows 0..511 x^T, 512..2047 h1, 2048..3583 h2, 3584..4095 out^T
// edges : slotted [NNODES][MAXDEG] int2 = 3,670,016
// cnt   : NNODES node-degree ints + 3*8 per-XCD work-queue ints
#define OFF_EDGES 33554432
#define OFF_CNT   (OFF_EDGES + (size_t)NNODES * MAXDEG * 8)

// ---------- x [B, N_IN] fp32 -> rows 0..511 of nv (fp16, [node][batch]) ----------
__global__ __launch_bounds__(256) void k_transpose_in(const float* __restrict__ x,
                                                      __half* __restrict__ xT) {
    __shared__ float tile[32][33];
    const int tx = threadIdx.x, ty = threadIdx.y;   // 32 x 8
    const int n0 = blockIdx.x * 32;
    const int b0 = blockIdx.y * 32;
#pragma unroll
    for (int k = 0; k < 32; k += 8)
        tile[ty + k][tx] = x[(size_t)(b0 + ty + k) * N_IN + (n0 + tx)];
    __syncthreads();
#pragma unroll
    for (int k = 0; k < 32; k += 8)
        xT[(size_t)(n0 + ty + k) * BATCH + (b0 + tx)] = __float2half_rn(tile[tx][ty + k]);
}

// ---------- slotted edge-table fill ----------
__global__ __launch_bounds__(256) void k_fill(const int* __restrict__ s0, const int* __restrict__ d0, const float* __restrict__ w0,
                                              const int* __restrict__ s1, const int* __restrict__ d1, const float* __restrict__ w1,
                                              const int* __restrict__ s2, const int* __restrict__ d2, const float* __restrict__ w2,
                                              int* __restrict__ cnt, int2* __restrict__ edges) {
    const int e = blockIdx.x * 256 + threadIdx.x;
    int src, node; float w;
    if (e < E0)           { src = s0[e];          node = d0[e];                w = w0[e]; }
    else if (e < E0 + E1) { int i = e - E0;       src = s1[i]; node = H1 + d1[i];        w = w1[i]; }
    else                  { int i = e - E0 - E1;  src = s2[i]; node = H1 + H2 + d2[i];   w = w2[i]; }
    const int pos = atomicAdd(&cnt[node], 1);
    if (pos < MAXDEG) edges[(size_t)node * MAXDEG + pos] = make_int2(src, __float_as_int(w));
}

// ---- gather-accumulate: one node, one 512-col tile (64 lanes x uint4 = 8 fp16 each) ----
// Edges staged in VGPRs (lane i holds edge i), consumed via readlane: scalar base,
// 8 independent 1KB gathers in flight per wave.
__device__ __forceinline__ void gather8(const int2* __restrict__ slot, int c, int col8,
                                        const uint4* __restrict__ nv, int lane, float* a) {
    for (int base = 0; base < c; base += 64) {
        const int2 my = slot[base + lane];            // MAXDEG=128: always in-bounds
        const int m = (c - base < 64) ? (c - base) : 64;
        int j = 0;
        for (; j + 8 <= m; j += 8) {
            uint4 q[8]; float w[8];
#pragma unroll
            for (int k = 0; k < 8; ++k) {
                const int s = __builtin_amdgcn_readlane(my.x, j + k) & 4095;
                w[k] = __int_as_float(__builtin_amdgcn_readlane(my.y, j + k));
                q[k] = nv[((size_t)s << 9) | col8];
            }
#pragma unroll
            for (int k = 0; k < 8; ++k) {
                const __half2* h = (const __half2*)&q[k];
#pragma unroll
                for (int p = 0; p < 4; ++p) {
                    a[2 * p]     = fmaf(__low2float(h[p]),  w[k], a[2 * p]);
                    a[2 * p + 1] = fmaf(__high2float(h[p]), w[k], a[2 * p + 1]);
                }
            }
        }
        for (; j < m; ++j) {
            const int s = __builtin_amdgcn_readlane(my.x, j) & 4095;
            const float wk = __int_as_float(__builtin_amdgcn_readlane(my.y, j));
            const uint4 qq = nv[((size_t)s << 9) | col8];
            const __half2* h = (const __half2*)&qq;
#pragma unroll
            for (int p = 0; p < 4; ++p) {
                a[2 * p]     = fmaf(__low2float(h[p]),  wk, a[2 * p]);
                a[2 * p + 1] = fmaf(__high2float(h[p]), wk, a[2 * p + 1]);
            }
        }
    }
}

// ---------- level kernel: per-XCD work queues, tile == physical XCD ----------
// Each wave reads its real XCD (s_getreg XCC_ID, [m09]), claims nodes from that
// XCD's queue (tile = queue id -> per-XCD gather footprint <= 3.58 MB, fits 4 MB L2),
// then steals from other queues so correctness never depends on dispatch mapping.
__global__ __launch_bounds__(256, 4)
void k_level(const int2* __restrict__ edges,   // level slot base
             const int* __restrict__ cnt,      // level node-degree base
             const uint4* __restrict__ nv,
             uint4* __restrict__ outb,         // level out row base (uint4 units)
             int* __restrict__ queues,         // 8 ints for this level (zeroed)
             int nnode) {
    const int lane = threadIdx.x & 63;
    unsigned xcc;
    asm volatile("s_getreg_b32 %0, hwreg(HW_REG_XCC_ID)" : "=s"(xcc));
    xcc &= 7u;

    for (int i = 0; i < 8; ++i) {
        const int t = (xcc + i) & 7;              // own queue first, then steal
        const int col8 = (t << 6) | lane;
        for (;;) {
            int nd0 = 0;
            if (lane == 0) nd0 = atomicAdd(&queues[t], 1);
            const int node = __builtin_amdgcn_readfirstlane(nd0);
            if (node >= nnode) break;
            int c = cnt[node];
            c = (c < 0) ? 0 : (c > MAXDEG ? MAXDEG : c);
            float a[8] = {0.f, 0.f, 0.f, 0.f, 0.f, 0.f, 0.f, 0.f};
            gather8(edges + (size_t)node * MAXDEG, c, col8, nv, lane, a);
#pragma unroll
            for (int k = 0; k < 8; ++k) a[k] = fmaxf(a[k], 0.f);
            const __half2 h0 = __floats2half2_rn(a[0], a[1]);
            const __half2 h1 = __floats2half2_rn(a[2], a[3]);
            const __half2 h2 = __floats2half2_rn(a[4], a[5]);
            const __half2 h3 = __floats2half2_rn(a[6], a[7]);
            uint4 p;
            p.x = *(const uint32_t*)&h0; p.y = *(const uint32_t*)&h1;
            p.z = *(const uint32_t*)&h2; p.w = *(const uint32_t*)&h3;
            outb[((size_t)node << 9) | col8] = p;
        }
    }
}

// ---------- out^T rows (fp16, [N_OUT][B]) -> d_out [B, N_OUT] fp32 ----------
__global__ __launch_bounds__(256) void k_transpose_out(const __half* __restrict__ outh,
                                                       float* __restrict__ out) {
    __shared__ float tile[32][33];
    const int tx = threadIdx.x, ty = threadIdx.y;   // 32 x 8
    const int n0 = blockIdx.x * 32;
    const int b0 = blockIdx.y * 32;
#pragma unroll
    for (int k = 0; k < 32; k += 8)
        tile[ty + k][tx] = __half2float(outh[(size_t)(n0 + ty + k) * BATCH + (b0 + tx)]);
    __syncthreads();
#pragma unroll
    for (int k = 0; k < 32; k += 8)
        out[(size_t)(b0 + ty + k) * N_OUT + (n0 + tx)] = tile[tx][ty + k];
}

extern "C" void kernel_launch(void* const* d_in, const int* in_sizes, int n_in,
                              void* d_out, int out_size, void* d_ws, size_t ws_size,
                              hipStream_t stream) {
    const float* x  = (const float*)d_in[0];
    const int* s0   = (const int*)d_in[1];
    const int* dd0  = (const int*)d_in[2];
    const float* w0 = (const float*)d_in[3];
    const int* s1   = (const int*)d_in[4];
    const int* dd1  = (const int*)d_in[5];
    const float* w1 = (const float*)d_in[6];
    const int* s2   = (const int*)d_in[7];
    const int* dd2  = (const int*)d_in[8];
    const float* w2 = (const float*)d_in[9];

    char*   ws    = (char*)d_ws;
    __half* nvh   = (__half*)ws;
    uint4*  nv4   = (uint4*)ws;
    int2*   edges = (int2*)(ws + OFF_EDGES);
    int*    cnt   = (int*)(ws + OFF_CNT);        // NNODES degrees + 24 queue slots

    // zero degrees + queues, then slotted edge fill (replay-idempotent)
    hipMemsetAsync(cnt, 0, (NNODES + 24) * sizeof(int), stream);
    k_fill<<<ETOT / 256, 256, 0, stream>>>(s0, dd0, w0, s1, dd1, w1, s2, dd2, w2, cnt, edges);

    // x -> fp16 transposed node-value rows 0..511
    k_transpose_in<<<dim3(N_IN / 32, BATCH / 32), dim3(32, 8), 0, stream>>>(x, nvh);

    // levels: 1024 blocks x 256 thr; per-XCD queues pin tile==XCD, stealing for safety
    k_level<<<1024, 256, 0, stream>>>(edges, cnt, nv4,
                                      nv4 + (size_t)N_IN * 512,
                                      cnt + NNODES, H1);
    k_level<<<1024, 256, 0, stream>>>(edges + (size_t)H1 * MAXDEG, cnt + H1, nv4,
                                      nv4 + (size_t)(N_IN + H1) * 512,
                                      cnt + NNODES + 8, H2);
    k_level<<<1024, 256, 0, stream>>>(edges + (size_t)(H1 + H2) * MAXDEG, cnt + H1 + H2, nv4,
                                      nv4 + (size_t)(N_IN + H1 + H2) * 512,
                                      cnt + NNODES + 16, N_OUT);

    // out^T (fp16) -> d_out [B, N_OUT] fp32
    k_transpose_out<<<dim3(N_OUT / 32, BATCH / 32), dim3(32, 8), 0, stream>>>(
        (const __half*)(ws + (size_t)(N_IN + H1 + H2) * BATCH * 2), (float*)d_out);
}

// Round 7
// 223.514 us; speedup vs baseline: 6.9348x; 6.9348x over previous
//
#include <hip/hip_runtime.h>
#include <hip/hip_fp16.h>
#include <stdint.h>

#define BATCH 4096
#define N_IN  512
#define H1    1536
#define H2    1536
#define N_OUT 512
#define E0 (H1 * 32)
#define E1 (H2 * 32)
#define E2 (N_OUT * 32)
#define ETOT (E0 + E1 + E2)
#define NNODES (H1 + H2 + N_OUT)   // 3584
#define MAXDEG 128
#define QSTRIDE 32                 // queue counter stride in ints (128 B, own cache line)

// ---- workspace layout (bytes), total ~37.24 MB (< 38.7 MB proven safe in R1) ----
// nv    : 4096 rows x 4096 cols x 2B fp16 = 33,554,432
//         rows 0..511 x^T, 512..2047 h1, 2048..3583 h2, 3584..4095 out^T
// edges : slotted [NNODES][MAXDEG] int2 = 3,670,016
// cnt   : NNODES node-degree ints + 3 levels * 8 queues * QSTRIDE ints
#define OFF_EDGES 33554432
#define OFF_CNT   (OFF_EDGES + (size_t)NNODES * MAXDEG * 8)

// ---------- x [B, N_IN] fp32 -> rows 0..511 of nv (fp16, [node][batch]) ----------
__global__ __launch_bounds__(256) void k_transpose_in(const float* __restrict__ x,
                                                      __half* __restrict__ xT) {
    __shared__ float tile[32][33];
    const int tx = threadIdx.x, ty = threadIdx.y;   // 32 x 8
    const int n0 = blockIdx.x * 32;
    const int b0 = blockIdx.y * 32;
#pragma unroll
    for (int k = 0; k < 32; k += 8)
        tile[ty + k][tx] = x[(size_t)(b0 + ty + k) * N_IN + (n0 + tx)];
    __syncthreads();
#pragma unroll
    for (int k = 0; k < 32; k += 8)
        xT[(size_t)(n0 + ty + k) * BATCH + (b0 + tx)] = __float2half_rn(tile[tx][ty + k]);
}

// ---------- slotted edge-table fill ----------
__global__ __launch_bounds__(256) void k_fill(const int* __restrict__ s0, const int* __restrict__ d0, const float* __restrict__ w0,
                                              const int* __restrict__ s1, const int* __restrict__ d1, const float* __restrict__ w1,
                                              const int* __restrict__ s2, const int* __restrict__ d2, const float* __restrict__ w2,
                                              int* __restrict__ cnt, int2* __restrict__ edges) {
    const int e = blockIdx.x * 256 + threadIdx.x;
    int src, node; float w;
    if (e < E0)           { src = s0[e];          node = d0[e];                w = w0[e]; }
    else if (e < E0 + E1) { int i = e - E0;       src = s1[i]; node = H1 + d1[i];        w = w1[i]; }
    else                  { int i = e - E0 - E1;  src = s2[i]; node = H1 + H2 + d2[i];   w = w2[i]; }
    const int pos = atomicAdd(&cnt[node], 1);
    if (pos < MAXDEG) edges[(size_t)node * MAXDEG + pos] = make_int2(src, __float_as_int(w));
}

// ---- gather-accumulate: one node, one 512-col tile (64 lanes x uint4 = 8 fp16 each) ----
__device__ __forceinline__ void gather8(const int2* __restrict__ slot, int c, int col8,
                                        const uint4* __restrict__ nv, int lane, float* a) {
    for (int base = 0; base < c; base += 64) {
        const int2 my = slot[base + lane];            // MAXDEG=128: always in-bounds
        const int m = (c - base < 64) ? (c - base) : 64;
        int j = 0;
        for (; j + 8 <= m; j += 8) {
            uint4 q[8]; float w[8];
#pragma unroll
            for (int k = 0; k < 8; ++k) {
                const int s = __builtin_amdgcn_readlane(my.x, j + k) & 4095;
                w[k] = __int_as_float(__builtin_amdgcn_readlane(my.y, j + k));
                q[k] = nv[((size_t)s << 9) | col8];
            }
#pragma unroll
            for (int k = 0; k < 8; ++k) {
                const __half2* h = (const __half2*)&q[k];
#pragma unroll
                for (int p = 0; p < 4; ++p) {
                    a[2 * p]     = fmaf(__low2float(h[p]),  w[k], a[2 * p]);
                    a[2 * p + 1] = fmaf(__high2float(h[p]), w[k], a[2 * p + 1]);
                }
            }
        }
        for (; j < m; ++j) {
            const int s = __builtin_amdgcn_readlane(my.x, j) & 4095;
            const float wk = __int_as_float(__builtin_amdgcn_readlane(my.y, j));
            const uint4 qq = nv[((size_t)s << 9) | col8];
            const __half2* h = (const __half2*)&qq;
#pragma unroll
            for (int p = 0; p < 4; ++p) {
                a[2 * p]     = fmaf(__low2float(h[p]),  wk, a[2 * p]);
                a[2 * p + 1] = fmaf(__high2float(h[p]), wk, a[2 * p + 1]);
            }
        }
    }
}

// ---------- level kernel: per-XCD quad queues (block-granularity claims) ----------
// All 4 waves of a block share one CU => one XCD (s_getreg XCC_ID, [m09]).
// Thread 0 claims a quad (4 nodes) from the block's own XCD queue: tile == XCD by
// construction (per-XCD gather footprint <= 3.58 MB, fits 4 MB L2). Queue counters
// are 128B-padded (no cross-XCD line ping-pong; R6's 500us atomic stall). Drained
// queues are detected with a plain load; stealing keeps correctness dispatch-independent.
__global__ __launch_bounds__(256, 4)
void k_level(const int2* __restrict__ edges,   // level slot base
             const int* __restrict__ cnt,      // level node-degree base
             const uint4* __restrict__ nv,
             uint4* __restrict__ outb,         // level out row base (uint4 units)
             int* __restrict__ queues,         // this level's 8 padded queue counters
             int nquad) {                      // nodes/4
    const int tid  = threadIdx.x;
    const int lane = tid & 63, wv = tid >> 6;
    unsigned xcc;
    asm volatile("s_getreg_b32 %0, hwreg(HW_REG_XCC_ID)" : "=s"(xcc));
    xcc &= 7u;

    __shared__ int s_q;
    for (int i = 0; i < 8; ++i) {
        const int t = (xcc + i) & 7;              // own queue first, then steal
        const int col8 = (t << 6) | lane;
        for (;;) {
            if (tid == 0) {
                int got = nquad;
                if (*(volatile int*)(queues + t * QSTRIDE) < nquad)   // cheap pre-check
                    got = atomicAdd(queues + t * QSTRIDE, 1);
                s_q = got;
            }
            __syncthreads();
            const int q = s_q;
            __syncthreads();
            if (q >= nquad) break;
            const int node = (q << 2) | wv;
            int c = cnt[node];
            c = (c < 0) ? 0 : (c > MAXDEG ? MAXDEG : c);
            float a[8] = {0.f, 0.f, 0.f, 0.f, 0.f, 0.f, 0.f, 0.f};
            gather8(edges + (size_t)node * MAXDEG, c, col8, nv, lane, a);
#pragma unroll
            for (int k = 0; k < 8; ++k) a[k] = fmaxf(a[k], 0.f);
            const __half2 h0 = __floats2half2_rn(a[0], a[1]);
            const __half2 h1 = __floats2half2_rn(a[2], a[3]);
            const __half2 h2 = __floats2half2_rn(a[4], a[5]);
            const __half2 h3 = __floats2half2_rn(a[6], a[7]);
            uint4 p;
            p.x = *(const uint32_t*)&h0; p.y = *(const uint32_t*)&h1;
            p.z = *(const uint32_t*)&h2; p.w = *(const uint32_t*)&h3;
            outb[((size_t)node << 9) | col8] = p;
        }
    }
}

// ---------- out^T rows (fp16, [N_OUT][B]) -> d_out [B, N_OUT] fp32 ----------
__global__ __launch_bounds__(256) void k_transpose_out(const __half* __restrict__ outh,
                                                       float* __restrict__ out) {
    __shared__ float tile[32][33];
    const int tx = threadIdx.x, ty = threadIdx.y;   // 32 x 8
    const int n0 = blockIdx.x * 32;
    const int b0 = blockIdx.y * 32;
#pragma unroll
    for (int k = 0; k < 32; k += 8)
        tile[ty + k][tx] = __half2float(outh[(size_t)(n0 + ty + k) * BATCH + (b0 + tx)]);
    __syncthreads();
#pragma unroll
    for (int k = 0; k < 32; k += 8)
        out[(size_t)(b0 + ty + k) * N_OUT + (n0 + tx)] = tile[tx][ty + k];
}

extern "C" void kernel_launch(void* const* d_in, const int* in_sizes, int n_in,
                              void* d_out, int out_size, void* d_ws, size_t ws_size,
                              hipStream_t stream) {
    const float* x  = (const float*)d_in[0];
    const int* s0   = (const int*)d_in[1];
    const int* dd0  = (const int*)d_in[2];
    const float* w0 = (const float*)d_in[3];
    const int* s1   = (const int*)d_in[4];
    const int* dd1  = (const int*)d_in[5];
    const float* w1 = (const float*)d_in[6];
    const int* s2   = (const int*)d_in[7];
    const int* dd2  = (const int*)d_in[8];
    const float* w2 = (const float*)d_in[9];

    char*   ws    = (char*)d_ws;
    __half* nvh   = (__half*)ws;
    uint4*  nv4   = (uint4*)ws;
    int2*   edges = (int2*)(ws + OFF_EDGES);
    int*    cnt   = (int*)(ws + OFF_CNT);        // NNODES degrees + 3*8*QSTRIDE queues
    int*    qs    = cnt + NNODES;

    // zero degrees + queues, then slotted edge fill (replay-idempotent)
    hipMemsetAsync(cnt, 0, (NNODES + 3 * 8 * QSTRIDE) * sizeof(int), stream);
    k_fill<<<ETOT / 256, 256, 0, stream>>>(s0, dd0, w0, s1, dd1, w1, s2, dd2, w2, cnt, edges);

    // x -> fp16 transposed node-value rows 0..511
    k_transpose_in<<<dim3(N_IN / 32, BATCH / 32), dim3(32, 8), 0, stream>>>(x, nvh);

    // levels: 1024 blocks x 256 thr; per-XCD quad queues pin tile==XCD
    k_level<<<1024, 256, 0, stream>>>(edges, cnt, nv4,
                                      nv4 + (size_t)N_IN * 512,
                                      qs, H1 / 4);
    k_level<<<1024, 256, 0, stream>>>(edges + (size_t)H1 * MAXDEG, cnt + H1, nv4,
                                      nv4 + (size_t)(N_IN + H1) * 512,
                                      qs + 8 * QSTRIDE, H2 / 4);
    k_level<<<1024, 256, 0, stream>>>(edges + (size_t)(H1 + H2) * MAXDEG, cnt + H1 + H2, nv4,
                                      nv4 + (size_t)(N_IN + H1 + H2) * 512,
                                      qs + 16 * QSTRIDE, N_OUT / 4);

    // out^T (fp16) -> d_out [B, N_OUT] fp32
    k_transpose_out<<<dim3(N_OUT / 32, BATCH / 32), dim3(32, 8), 0, stream>>>(
        (const __half*)(ws + (size_t)(N_IN + H1 + H2) * BATCH * 2), (float*)d_out);
}

// Round 8
// 151.410 us; speedup vs baseline: 10.2372x; 1.4762x over previous
//
#include <hip/hip_runtime.h>
#include <hip/hip_fp16.h>
#include <stdint.h>

#define BATCH 4096
#define N_IN  512
#define H1    1536
#define H2    1536
#define N_OUT 512
#define E0 (H1 * 32)
#define E1 (H2 * 32)
#define E2 (N_OUT * 32)
#define ETOT (E0 + E1 + E2)
#define NNODES (H1 + H2 + N_OUT)   // 3584
#define MAXDEG 128

// ---- workspace layout (bytes), total ~37.24 MB (< 38.7 MB proven safe in R1) ----
// nv    : 4096 rows x 4096 cols x 2B fp16 = 33,554,432
//         rows 0..511 x^T, 512..2047 h1, 2048..3583 h2, 3584..4095 out^T
// edges : slotted [NNODES][MAXDEG] int2 = 3,670,016
// cnt   : NNODES node-degree ints
#define OFF_EDGES 33554432
#define OFF_CNT   (OFF_EDGES + (size_t)NNODES * MAXDEG * 8)

// ---------- x [B, N_IN] fp32 -> rows 0..511 of nv (fp16, [node][batch]) ----------
__global__ __launch_bounds__(256) void k_transpose_in(const float* __restrict__ x,
                                                      __half* __restrict__ xT) {
    __shared__ float tile[32][33];
    const int tx = threadIdx.x, ty = threadIdx.y;   // 32 x 8
    const int n0 = blockIdx.x * 32;
    const int b0 = blockIdx.y * 32;
#pragma unroll
    for (int k = 0; k < 32; k += 8)
        tile[ty + k][tx] = x[(size_t)(b0 + ty + k) * N_IN + (n0 + tx)];
    __syncthreads();
#pragma unroll
    for (int k = 0; k < 32; k += 8)
        xT[(size_t)(n0 + ty + k) * BATCH + (b0 + tx)] = __float2half_rn(tile[tx][ty + k]);
}

// ---------- slotted edge-table fill ----------
__global__ __launch_bounds__(256) void k_fill(const int* __restrict__ s0, const int* __restrict__ d0, const float* __restrict__ w0,
                                              const int* __restrict__ s1, const int* __restrict__ d1, const float* __restrict__ w1,
                                              const int* __restrict__ s2, const int* __restrict__ d2, const float* __restrict__ w2,
                                              int* __restrict__ cnt, int2* __restrict__ edges) {
    const int e = blockIdx.x * 256 + threadIdx.x;
    int src, node; float w;
    if (e < E0)           { src = s0[e];          node = d0[e];                w = w0[e]; }
    else if (e < E0 + E1) { int i = e - E0;       src = s1[i]; node = H1 + d1[i];        w = w1[i]; }
    else                  { int i = e - E0 - E1;  src = s2[i]; node = H1 + H2 + d2[i];   w = w2[i]; }
    const int pos = atomicAdd(&cnt[node], 1);
    if (pos < MAXDEG) edges[(size_t)node * MAXDEG + pos] = make_int2(src, __float_as_int(w));
}

// ---------- pad each node's slot list to a multiple of 8 with {src=0, w=0} ----------
// Removes the serialized tail in k_level: every inner iteration is a full 8-deep
// load pipeline. w=0 contributes nothing; src=0 is a valid row (x values).
__global__ __launch_bounds__(256) void k_pad(const int* __restrict__ cnt,
                                             int2* __restrict__ edges) {
    const int i = blockIdx.x * 256 + threadIdx.x;   // NNODES*8 threads
    const int node = i >> 3, p = i & 7;
    if (node >= NNODES) return;
    int c = cnt[node];
    c = (c < 0) ? 0 : (c > MAXDEG - 8 ? MAXDEG - 8 : c);
    edges[(size_t)node * MAXDEG + c + p] = make_int2(0, 0);
}

// ---------- level kernel: grid (8 col-tiles, H/4 quads), 256 thr = 4 waves = 4 nodes ----
// Bottleneck per R7 counters is exposed L2 latency (VALUBusy 18%, VGPR 32 => compiler
// serialized the q[] pipeline). Fix: 8 NAMED uint4 loads in flight (no array),
// launch_bounds(256,2) lifts the VGPR cap so the pipeline stays in registers.
__global__ __launch_bounds__(256, 2)
void k_level(const int2* __restrict__ edges,   // level slot base
             const int* __restrict__ cnt,      // level node-degree base
             const uint4* __restrict__ nv,
             uint4* __restrict__ outb) {       // level out row base (uint4 units)
    const int tid  = threadIdx.x;
    const int lane = tid & 63, wv = tid >> 6;
    const int node = (blockIdx.y << 2) | wv;
    const int col8 = ((int)blockIdx.x << 6) | lane;   // uint4 index in row, 0..511

    int c = cnt[node];
    c = (c < 0) ? 0 : (c > MAXDEG - 8 ? MAXDEG - 8 : c);
    const int cp = (c + 7) & ~7;                      // padded degree (k_pad guarantees slots)

    float a0 = 0.f, a1 = 0.f, a2 = 0.f, a3 = 0.f, a4 = 0.f, a5 = 0.f, a6 = 0.f, a7 = 0.f;
    const int2* slot = edges + (size_t)node * MAXDEG;

#define LOADK(k)                                                               \
    const int   s##k = __builtin_amdgcn_readlane(my.x, j + k) & 4095;          \
    const float w##k = __int_as_float(__builtin_amdgcn_readlane(my.y, j + k)); \
    const uint4 q##k = nv[((size_t)s##k << 9) | col8];

#define ACCK(k) {                                                  \
    const __half2* h = (const __half2*)&q##k;                      \
    a0 = fmaf(__low2float(h[0]),  w##k, a0);                       \
    a1 = fmaf(__high2float(h[0]), w##k, a1);                       \
    a2 = fmaf(__low2float(h[1]),  w##k, a2);                       \
    a3 = fmaf(__high2float(h[1]), w##k, a3);                       \
    a4 = fmaf(__low2float(h[2]),  w##k, a4);                       \
    a5 = fmaf(__high2float(h[2]), w##k, a5);                       \
    a6 = fmaf(__low2float(h[3]),  w##k, a6);                       \
    a7 = fmaf(__high2float(h[3]), w##k, a7); }

    for (int base = 0; base < cp; base += 64) {
        const int2 my = slot[base + lane];            // MAXDEG slots: always in-bounds
        const int m = (cp - base < 64) ? (cp - base) : 64;
        for (int j = 0; j < m; j += 8) {              // all-full 8-deep iterations
            LOADK(0) LOADK(1) LOADK(2) LOADK(3)
            LOADK(4) LOADK(5) LOADK(6) LOADK(7)
            ACCK(0) ACCK(1) ACCK(2) ACCK(3)
            ACCK(4) ACCK(5) ACCK(6) ACCK(7)
        }
    }
#undef LOADK
#undef ACCK

    a0 = fmaxf(a0, 0.f); a1 = fmaxf(a1, 0.f); a2 = fmaxf(a2, 0.f); a3 = fmaxf(a3, 0.f);
    a4 = fmaxf(a4, 0.f); a5 = fmaxf(a5, 0.f); a6 = fmaxf(a6, 0.f); a7 = fmaxf(a7, 0.f);

    const __half2 h0 = __floats2half2_rn(a0, a1);
    const __half2 h1 = __floats2half2_rn(a2, a3);
    const __half2 h2 = __floats2half2_rn(a4, a5);
    const __half2 h3 = __floats2half2_rn(a6, a7);
    uint4 p;
    p.x = *(const uint32_t*)&h0; p.y = *(const uint32_t*)&h1;
    p.z = *(const uint32_t*)&h2; p.w = *(const uint32_t*)&h3;
    outb[((size_t)node << 9) | col8] = p;
}

// ---------- out^T rows (fp16, [N_OUT][B]) -> d_out [B, N_OUT] fp32 ----------
__global__ __launch_bounds__(256) void k_transpose_out(const __half* __restrict__ outh,
                                                       float* __restrict__ out) {
    __shared__ float tile[32][33];
    const int tx = threadIdx.x, ty = threadIdx.y;   // 32 x 8
    const int n0 = blockIdx.x * 32;
    const int b0 = blockIdx.y * 32;
#pragma unroll
    for (int k = 0; k < 32; k += 8)
        tile[ty + k][tx] = __half2float(outh[(size_t)(n0 + ty + k) * BATCH + (b0 + tx)]);
    __syncthreads();
#pragma unroll
    for (int k = 0; k < 32; k += 8)
        out[(size_t)(b0 + ty + k) * N_OUT + (n0 + tx)] = tile[tx][ty + k];
}

extern "C" void kernel_launch(void* const* d_in, const int* in_sizes, int n_in,
                              void* d_out, int out_size, void* d_ws, size_t ws_size,
                              hipStream_t stream) {
    const float* x  = (const float*)d_in[0];
    const int* s0   = (const int*)d_in[1];
    const int* dd0  = (const int*)d_in[2];
    const float* w0 = (const float*)d_in[3];
    const int* s1   = (const int*)d_in[4];
    const int* dd1  = (const int*)d_in[5];
    const float* w1 = (const float*)d_in[6];
    const int* s2   = (const int*)d_in[7];
    const int* dd2  = (const int*)d_in[8];
    const float* w2 = (const float*)d_in[9];

    char*   ws    = (char*)d_ws;
    __half* nvh   = (__half*)ws;
    uint4*  nv4   = (uint4*)ws;
    int2*   edges = (int2*)(ws + OFF_EDGES);
    int*    cnt   = (int*)(ws + OFF_CNT);

    // zero degrees, slotted edge fill, pad degrees to x8 (replay-idempotent)
    hipMemsetAsync(cnt, 0, NNODES * sizeof(int), stream);
    k_fill<<<ETOT / 256, 256, 0, stream>>>(s0, dd0, w0, s1, dd1, w1, s2, dd2, w2, cnt, edges);
    k_pad<<<(NNODES * 8 + 255) / 256, 256, 0, stream>>>(cnt, edges);

    // x -> fp16 transposed node-value rows 0..511
    k_transpose_in<<<dim3(N_IN / 32, BATCH / 32), dim3(32, 8), 0, stream>>>(x, nvh);

    // levels: grid (8 col-tiles, H/4 quads), 256 thr
    k_level<<<dim3(8, H1 / 4), 256, 0, stream>>>(edges, cnt, nv4,
                                                 nv4 + (size_t)N_IN * 512);
    k_level<<<dim3(8, H2 / 4), 256, 0, stream>>>(edges + (size_t)H1 * MAXDEG, cnt + H1, nv4,
                                                 nv4 + (size_t)(N_IN + H1) * 512);
    k_level<<<dim3(8, N_OUT / 4), 256, 0, stream>>>(edges + (size_t)(H1 + H2) * MAXDEG, cnt + H1 + H2, nv4,
                                                    nv4 + (size_t)(N_IN + H1 + H2) * 512);

    // out^T (fp16) -> d_out [B, N_OUT] fp32
    k_transpose_out<<<dim3(N_OUT / 32, BATCH / 32), dim3(32, 8), 0, stream>>>(
        (const __half*)(ws + (size_t)(N_IN + H1 + H2) * BATCH * 2), (float*)d_out);
}